// Round 1
// 234.164 us; speedup vs baseline: 1.0533x; 1.0533x over previous
//
#include <hip/hip_runtime.h>

// Problem constants (B,C,H,W)=(32,64,64,64), code_size=512
#define HWDIM 4096
#define CDIM  64
#define KDIM  512
#define ST_ELEMS   8388608   // 32*64*64*64
#define LOSS_OFF   8519680   // ST_ELEMS + 32*64*64

#define REP64(M) M(0) M(1) M(2) M(3) M(4) M(5) M(6) M(7) M(8) M(9) \
  M(10) M(11) M(12) M(13) M(14) M(15) M(16) M(17) M(18) M(19) \
  M(20) M(21) M(22) M(23) M(24) M(25) M(26) M(27) M(28) M(29) \
  M(30) M(31) M(32) M(33) M(34) M(35) M(36) M(37) M(38) M(39) \
  M(40) M(41) M(42) M(43) M(44) M(45) M(46) M(47) M(48) M(49) \
  M(50) M(51) M(52) M(53) M(54) M(55) M(56) M(57) M(58) M(59) \
  M(60) M(61) M(62) M(63)

// 16-float vector -> s_load_dwordx16 when loaded via constant address space.
typedef float vf16 __attribute__((ext_vector_type(16)));
typedef __attribute__((address_space(4))) const vf16 cvf16;

// numpy fp32 pairwise sum-of-squares of 64 contiguous values (AVX-512 npyv
// emulation) — bit-validated R1-R5.
__device__ __forceinline__ float np_sumsq64(const float a[64]) {
#pragma clang fp contract(off)
  float v[16];
#pragma unroll
  for (int i = 0; i < 16; ++i) {
    float s0 = a[i]      * a[i];
    float s1 = a[i + 16] * a[i + 16];
    float s2 = a[i + 32] * a[i + 32];
    float s3 = a[i + 48] * a[i + 48];
    v[i] = (s0 + s1) + (s2 + s3);
  }
  float t0 = (v[0] + v[8])  + (v[4] + v[12]);
  float t1 = (v[1] + v[9])  + (v[5] + v[13]);
  float t2 = (v[2] + v[10]) + (v[6] + v[14]);
  float t3 = (v[3] + v[11]) + (v[7] + v[15]);
  return (t0 + t2) + (t1 + t3);
}

// R6: in-block K-split. 512-thread blocks: waves 0-3 (khalf=0) scan codes
// 0..255 for pixels 0..255, waves 4-7 (khalf=1) scan codes 256..511 for the
// SAME pixels. Argmin merged via packed (dist_bits<<32|idx) u64 min in LDS —
// exactly reproduces the serial strict-< first-min scan (positive dists ->
// float bits monotonic; equal dist -> lower idx wins). Doubles waves/SIMD
// 2 -> 4 to hide the per-chunk ~200-cyc scalar-load (L2) latency that the
// SGPR budget (112 regs -> no prefetch double-buffer) cannot hide in-wave.
// All FMA chains / sumsq trees / loss tree bit-identical to R5.
__global__ __launch_bounds__(512)
__attribute__((amdgpu_waves_per_eu(4, 4)))
void vq_kernel(
    const float* __restrict__ x, const float* __restrict__ cb,
    float* __restrict__ st, float* __restrict__ idxo, float* __restrict__ loss)
{
  __shared__ float sc[KDIM];
  __shared__ unsigned long long mrg[256];
  __shared__ float lred[8];

  const int tid = threadIdx.x;
  const int pix = tid & 255;                       // pixel slot in block
  // readfirstlane: tid>>8 IS wave-uniform (64-aligned waves never straddle a
  // 256 boundary) but divergence analysis can't prove it; force SGPR so the
  // row addresses below stay scalar -> s_load_dwordx16 (vector-load fallback
  // is the known 208us broadcast-BW plateau).
  const int khalf = __builtin_amdgcn_readfirstlane(tid >> 8);
  const int b   = blockIdx.x & 31;                 // batch index
  const int p   = ((blockIdx.x >> 5) << 8) + pix;  // pixel index 0..4095

  // Constant-AS view of the codebook: wave-uniform row addresses -> the
  // backend emits s_load_dwordx16 (scalar pipe). R1-R5 evidence: rows via
  // vector loads (global OR LDS) all plateau at ~208us = broadcast
  // data-return bandwidth; SGPR rows remove that traffic entirely.
  cvf16* rows = (cvf16*)(uintptr_t)cb;   // row k = chunks [4k .. 4k+3]

  // Per-block codebook sum-of-squares (per-lane k -> divergent: vector loads).
  // 512 threads -> exactly one row each.
  for (int k = tid; k < KDIM; k += 512) {
    float row[64];
#pragma unroll
    for (int c = 0; c < 64; ++c) row[c] = cb[(k << 6) + c];
    sc[k] = np_sumsq64(row);
  }

  // Load this thread's point into 64 named, pinned registers.
  const float* xp = x + (size_t)b * (CDIM * HWDIM) + p;
#define XLOAD(i) float x##i = xp[(i) * HWDIM]; asm("" : "+v"(x##i));
  REP64(XLOAD)
#undef XLOAD

  // numpy pairwise sum-of-squares of x (same tree, named-register form).
  float S;
  {
#pragma clang fp contract(off)
#define SQ(i, j, k2, l) float v##i = ((x##i * x##i) + (x##j * x##j)) + ((x##k2 * x##k2) + (x##l * x##l));
    SQ(0,16,32,48) SQ(1,17,33,49) SQ(2,18,34,50) SQ(3,19,35,51)
    SQ(4,20,36,52) SQ(5,21,37,53) SQ(6,22,38,54) SQ(7,23,39,55)
    SQ(8,24,40,56) SQ(9,25,41,57) SQ(10,26,42,58) SQ(11,27,43,59)
    SQ(12,28,44,60) SQ(13,29,45,61) SQ(14,30,46,62) SQ(15,31,47,63)
#undef SQ
    float t0 = (v0 + v8)  + (v4 + v12);
    float t1 = (v1 + v9)  + (v5 + v13);
    float t2 = (v2 + v10) + (v6 + v14);
    float t3 = (v3 + v11) + (v7 + v15);
    S = (t0 + t2) + (t1 + t3);
  }
  __syncthreads();

  // Argmin over this half's 256 codes, 4 rows per iteration, rows streamed
  // through SGPRs in 16-float chunks. Per-chain FMA order is ascending c —
  // bit-identical to R1-R5.
  float bestd = __builtin_inff();
  int   besti = 0;
  const int k0 = khalf << 8;

#define FF(T, XI) \
    d0 = __builtin_fmaf(x##XI, c0[T], d0); \
    d1 = __builtin_fmaf(x##XI, c1[T], d1); \
    d2 = __builtin_fmaf(x##XI, c2[T], d2); \
    d3 = __builtin_fmaf(x##XI, c3[T], d3);
#define CHUNK(J, A0,A1,A2,A3,A4,A5,A6,A7,A8,A9,A10,A11,A12,A13,A14,A15) \
  { vf16 c0 = rows[rb + (J)];      vf16 c1 = rows[rb + 4 + (J)];        \
    vf16 c2 = rows[rb + 8 + (J)];  vf16 c3 = rows[rb + 12 + (J)];       \
    FF(0,A0) FF(1,A1) FF(2,A2) FF(3,A3) FF(4,A4) FF(5,A5) FF(6,A6)      \
    FF(7,A7) FF(8,A8) FF(9,A9) FF(10,A10) FF(11,A11) FF(12,A12)         \
    FF(13,A13) FF(14,A14) FF(15,A15) }

  for (int k = k0; k < k0 + 256; k += 4) {
    const int rb = k << 2;            // x16-chunk index of row k
    float d0 = 0.f, d1 = 0.f, d2 = 0.f, d3 = 0.f;
    CHUNK(0,  0, 1, 2, 3, 4, 5, 6, 7, 8, 9,10,11,12,13,14,15)
    CHUNK(1, 16,17,18,19,20,21,22,23,24,25,26,27,28,29,30,31)
    CHUNK(2, 32,33,34,35,36,37,38,39,40,41,42,43,44,45,46,47)
    CHUNK(3, 48,49,50,51,52,53,54,55,56,57,58,59,60,61,62,63)
    float e0, e1, e2, e3;
    {
#pragma clang fp contract(off)
      e0 = (S - (d0 + d0)) + sc[k];
      e1 = (S - (d1 + d1)) + sc[k + 1];
      e2 = (S - (d2 + d2)) + sc[k + 2];
      e3 = (S - (d3 + d3)) + sc[k + 3];
    }
    if (e0 < bestd) { bestd = e0; besti = k; }
    if (e1 < bestd) { bestd = e1; besti = k + 1; }
    if (e2 < bestd) { bestd = e2; besti = k + 2; }
    if (e3 < bestd) { bestd = e3; besti = k + 3; }
  }
#undef CHUNK
#undef FF

  // Cross-half argmin merge. Distances are ~64 (strictly positive) so fp32
  // bit patterns order identically to the floats; packing idx in the low
  // word makes u64-min reproduce "first minimum wins" exactly.
  unsigned long long pk =
      ((unsigned long long)__float_as_uint(bestd) << 32) | (unsigned)besti;
  if (khalf) mrg[pix] = pk;
  __syncthreads();

  float lsum = 0.f;
  if (!khalf) {
    { unsigned long long o = mrg[pix]; if (o < pk) pk = o; }
    besti = (int)(pk & 0xffffffffull);

    // Gather chosen code row (per-lane divergent -> vector loads), write st
    // (coalesced: lane = consecutive p), accumulate loss partial. Identical
    // to R5's epilogue (half-0 waves only -> loss tree bit-identical).
    const float* crow = cb + (besti << 6);
    float* stp = st + (size_t)b * (CDIM * HWDIM) + p;
#define EPI(i) { float cv = crow[i]; float df; \
    { _Pragma("clang fp contract(off)") df = cv - x##i; } \
    lsum = __builtin_fmaf(df, df, lsum); stp[(i) * HWDIM] = cv; }
    REP64(EPI)
#undef EPI

    // indices[b, p] as float (d_out is one flat float32 buffer).
    idxo[b * HWDIM + p] = (float)besti;
  }

  // Block reduce loss, one atomic per block. Waves 4-7 contribute exact
  // zeros: t + 0.0f == t bitwise for the nonnegative sums here, so the
  // result is bit-identical to the R5 4-wave reduction.
#pragma unroll
  for (int off = 32; off > 0; off >>= 1) lsum += __shfl_down(lsum, off);
  if ((tid & 63) == 0) lred[tid >> 6] = lsum;
  __syncthreads();
  if (tid == 0) {
    float t = ((lred[0] + lred[1]) + (lred[2] + lred[3]))
            + ((lred[4] + lred[5]) + (lred[6] + lred[7]));
    atomicAdd(loss, t * (1.25f / 8388608.f));
  }
}

extern "C" void kernel_launch(void* const* d_in, const int* in_sizes, int n_in,
                              void* d_out, int out_size, void* d_ws, size_t ws_size,
                              hipStream_t stream) {
  const float* x  = (const float*)d_in[0];   // (32,64,64,64) fp32
  const float* cb = (const float*)d_in[1];   // (512,64) fp32
  float* st   = (float*)d_out;               // (32,64,64,64)
  float* idxo = (float*)d_out + ST_ELEMS;    // (32,64,64) as float
  float* loss = (float*)d_out + LOSS_OFF;    // scalar

  hipMemsetAsync(loss, 0, sizeof(float), stream);  // d_out is poisoned each call
  vq_kernel<<<dim3(512), dim3(512), 0, stream>>>(x, cb, st, idxo, loss);
}

// Round 2
// 230.851 us; speedup vs baseline: 1.0684x; 1.0144x over previous
//
#include <hip/hip_runtime.h>

// Problem constants (B,C,H,W)=(32,64,64,64), code_size=512
#define HWDIM 4096
#define CDIM  64
#define KDIM  512
#define ST_ELEMS   8388608   // 32*64*64*64
#define LOSS_OFF   8519680   // ST_ELEMS + 32*64*64

#define REP64(M) M(0) M(1) M(2) M(3) M(4) M(5) M(6) M(7) M(8) M(9) \
  M(10) M(11) M(12) M(13) M(14) M(15) M(16) M(17) M(18) M(19) \
  M(20) M(21) M(22) M(23) M(24) M(25) M(26) M(27) M(28) M(29) \
  M(30) M(31) M(32) M(33) M(34) M(35) M(36) M(37) M(38) M(39) \
  M(40) M(41) M(42) M(43) M(44) M(45) M(46) M(47) M(48) M(49) \
  M(50) M(51) M(52) M(53) M(54) M(55) M(56) M(57) M(58) M(59) \
  M(60) M(61) M(62) M(63)

// 16-float vector -> s_load_dwordx16 when loaded via constant address space.
typedef float vf16 __attribute__((ext_vector_type(16)));
typedef __attribute__((address_space(4))) const vf16 cvf16;

// numpy fp32 pairwise sum-of-squares of 64 contiguous values (AVX-512 npyv
// emulation) — bit-validated R1-R5.
__device__ __forceinline__ float np_sumsq64(const float a[64]) {
#pragma clang fp contract(off)
  float v[16];
#pragma unroll
  for (int i = 0; i < 16; ++i) {
    float s0 = a[i]      * a[i];
    float s1 = a[i + 16] * a[i + 16];
    float s2 = a[i + 32] * a[i + 32];
    float s3 = a[i + 48] * a[i + 48];
    v[i] = (s0 + s1) + (s2 + s3);
  }
  float t0 = (v[0] + v[8])  + (v[4] + v[12]);
  float t1 = (v[1] + v[9])  + (v[5] + v[13]);
  float t2 = (v[2] + v[10]) + (v[6] + v[14]);
  float t3 = (v[3] + v[11]) + (v[7] + v[15]);
  return (t0 + t2) + (t1 + t3);
}

// R6: in-block K-split (waves 0-3 codes 0..255, waves 4-7 codes 256..511 for
// the same 256 pixels), u64-packed argmin merge in LDS. 4 waves/SIMD.
// R7: K$-lockstep barriers. SMEM returns are out-of-order on gfx9 -> only
// lgkmcnt(0) is meaningful -> scalar-load latency per chunk is exposed and
// un-pipelineable. The 16KB scalar cache holds 1/8th of the codebook; waves
// drifting apart thrash it and chunk loads miss to L2 (~500+cyc scalar).
// __syncthreads() every 4 k-groups pins all 8 waves of a block into a 4KB
// read window (x 2 halves x 2 blocks/CU = 16KB = K$), so the front-runner's
// miss prefetches for the other 7 waves. Barriers are uniform control flow
// and touch no FP op — arithmetic bit-identical to R5/R6.
__global__ __launch_bounds__(512)
__attribute__((amdgpu_waves_per_eu(4, 4)))
void vq_kernel(
    const float* __restrict__ x, const float* __restrict__ cb,
    float* __restrict__ st, float* __restrict__ idxo, float* __restrict__ loss)
{
  __shared__ float sc[KDIM];
  __shared__ unsigned long long mrg[256];
  __shared__ float lred[8];

  const int tid = threadIdx.x;
  const int pix = tid & 255;                       // pixel slot in block
  // readfirstlane: tid>>8 IS wave-uniform (64-aligned waves never straddle a
  // 256 boundary) but divergence analysis can't prove it; force SGPR so the
  // row addresses below stay scalar -> s_load_dwordx16 (vector-load fallback
  // is the known 208us broadcast-BW plateau).
  const int khalf = __builtin_amdgcn_readfirstlane(tid >> 8);
  const int b   = blockIdx.x & 31;                 // batch index
  const int p   = ((blockIdx.x >> 5) << 8) + pix;  // pixel index 0..4095

  // Constant-AS view of the codebook: wave-uniform row addresses -> the
  // backend emits s_load_dwordx16 (scalar pipe). R1-R5 evidence: rows via
  // vector loads (global OR LDS) all plateau at ~208us = broadcast
  // data-return bandwidth; SGPR rows remove that traffic entirely.
  cvf16* rows = (cvf16*)(uintptr_t)cb;   // row k = chunks [4k .. 4k+3]

  // Per-block codebook sum-of-squares (per-lane k -> divergent: vector loads).
  // 512 threads -> exactly one row each.
  for (int k = tid; k < KDIM; k += 512) {
    float row[64];
#pragma unroll
    for (int c = 0; c < 64; ++c) row[c] = cb[(k << 6) + c];
    sc[k] = np_sumsq64(row);
  }

  // Load this thread's point into 64 named, pinned registers.
  const float* xp = x + (size_t)b * (CDIM * HWDIM) + p;
#define XLOAD(i) float x##i = xp[(i) * HWDIM]; asm("" : "+v"(x##i));
  REP64(XLOAD)
#undef XLOAD

  // numpy pairwise sum-of-squares of x (same tree, named-register form).
  float S;
  {
#pragma clang fp contract(off)
#define SQ(i, j, k2, l) float v##i = ((x##i * x##i) + (x##j * x##j)) + ((x##k2 * x##k2) + (x##l * x##l));
    SQ(0,16,32,48) SQ(1,17,33,49) SQ(2,18,34,50) SQ(3,19,35,51)
    SQ(4,20,36,52) SQ(5,21,37,53) SQ(6,22,38,54) SQ(7,23,39,55)
    SQ(8,24,40,56) SQ(9,25,41,57) SQ(10,26,42,58) SQ(11,27,43,59)
    SQ(12,28,44,60) SQ(13,29,45,61) SQ(14,30,46,62) SQ(15,31,47,63)
#undef SQ
    float t0 = (v0 + v8)  + (v4 + v12);
    float t1 = (v1 + v9)  + (v5 + v13);
    float t2 = (v2 + v10) + (v6 + v14);
    float t3 = (v3 + v11) + (v7 + v15);
    S = (t0 + t2) + (t1 + t3);
  }
  __syncthreads();

  // Argmin over this half's 256 codes, 4 rows per iteration, rows streamed
  // through SGPRs in 16-float chunks. Per-chain FMA order is ascending c —
  // bit-identical to R1-R5.
  float bestd = __builtin_inff();
  int   besti = 0;
  const int k0 = khalf << 8;

#define FF(T, XI) \
    d0 = __builtin_fmaf(x##XI, c0[T], d0); \
    d1 = __builtin_fmaf(x##XI, c1[T], d1); \
    d2 = __builtin_fmaf(x##XI, c2[T], d2); \
    d3 = __builtin_fmaf(x##XI, c3[T], d3);
#define CHUNK(J, A0,A1,A2,A3,A4,A5,A6,A7,A8,A9,A10,A11,A12,A13,A14,A15) \
  { vf16 c0 = rows[rb + (J)];      vf16 c1 = rows[rb + 4 + (J)];        \
    vf16 c2 = rows[rb + 8 + (J)];  vf16 c3 = rows[rb + 12 + (J)];       \
    FF(0,A0) FF(1,A1) FF(2,A2) FF(3,A3) FF(4,A4) FF(5,A5) FF(6,A6)      \
    FF(7,A7) FF(8,A8) FF(9,A9) FF(10,A10) FF(11,A11) FF(12,A12)         \
    FF(13,A13) FF(14,A14) FF(15,A15) }
#define KGROUP(K) \
  { const int k = (K); \
    const int rb = k << 2; \
    float d0 = 0.f, d1 = 0.f, d2 = 0.f, d3 = 0.f; \
    CHUNK(0,  0, 1, 2, 3, 4, 5, 6, 7, 8, 9,10,11,12,13,14,15) \
    CHUNK(1, 16,17,18,19,20,21,22,23,24,25,26,27,28,29,30,31) \
    CHUNK(2, 32,33,34,35,36,37,38,39,40,41,42,43,44,45,46,47) \
    CHUNK(3, 48,49,50,51,52,53,54,55,56,57,58,59,60,61,62,63) \
    float e0, e1, e2, e3; \
    { \
      _Pragma("clang fp contract(off)") \
      e0 = (S - (d0 + d0)) + sc[k]; \
      e1 = (S - (d1 + d1)) + sc[k + 1]; \
      e2 = (S - (d2 + d2)) + sc[k + 2]; \
      e3 = (S - (d3 + d3)) + sc[k + 3]; \
    } \
    if (e0 < bestd) { bestd = e0; besti = k; } \
    if (e1 < bestd) { bestd = e1; besti = k + 1; } \
    if (e2 < bestd) { bestd = e2; besti = k + 2; } \
    if (e3 < bestd) { bestd = e3; besti = k + 3; } }

  // 16 outer iterations x 4 k-groups, lockstep barrier per outer iteration.
  for (int kk = k0; kk < k0 + 256; kk += 16) {
    KGROUP(kk)
    KGROUP(kk + 4)
    KGROUP(kk + 8)
    KGROUP(kk + 12)
    __syncthreads();
  }
#undef KGROUP
#undef CHUNK
#undef FF

  // Cross-half argmin merge. Distances are ~64 (strictly positive) so fp32
  // bit patterns order identically to the floats; packing idx in the low
  // word makes u64-min reproduce "first minimum wins" exactly.
  unsigned long long pk =
      ((unsigned long long)__float_as_uint(bestd) << 32) | (unsigned)besti;
  if (khalf) mrg[pix] = pk;
  __syncthreads();

  float lsum = 0.f;
  if (!khalf) {
    { unsigned long long o = mrg[pix]; if (o < pk) pk = o; }
    besti = (int)(pk & 0xffffffffull);

    // Gather chosen code row (per-lane divergent -> vector loads), write st
    // (coalesced: lane = consecutive p), accumulate loss partial. Identical
    // to R5's epilogue (half-0 waves only -> loss tree bit-identical).
    const float* crow = cb + (besti << 6);
    float* stp = st + (size_t)b * (CDIM * HWDIM) + p;
#define EPI(i) { float cv = crow[i]; float df; \
    { _Pragma("clang fp contract(off)") df = cv - x##i; } \
    lsum = __builtin_fmaf(df, df, lsum); stp[(i) * HWDIM] = cv; }
    REP64(EPI)
#undef EPI

    // indices[b, p] as float (d_out is one flat float32 buffer).
    idxo[b * HWDIM + p] = (float)besti;
  }

  // Block reduce loss, one atomic per block. Waves 4-7 contribute exact
  // zeros: t + 0.0f == t bitwise for the nonnegative sums here, so the
  // result is bit-identical to the R5 4-wave reduction.
#pragma unroll
  for (int off = 32; off > 0; off >>= 1) lsum += __shfl_down(lsum, off);
  if ((tid & 63) == 0) lred[tid >> 6] = lsum;
  __syncthreads();
  if (tid == 0) {
    float t = ((lred[0] + lred[1]) + (lred[2] + lred[3]))
            + ((lred[4] + lred[5]) + (lred[6] + lred[7]));
    atomicAdd(loss, t * (1.25f / 8388608.f));
  }
}

extern "C" void kernel_launch(void* const* d_in, const int* in_sizes, int n_in,
                              void* d_out, int out_size, void* d_ws, size_t ws_size,
                              hipStream_t stream) {
  const float* x  = (const float*)d_in[0];   // (32,64,64,64) fp32
  const float* cb = (const float*)d_in[1];   // (512,64) fp32
  float* st   = (float*)d_out;               // (32,64,64,64)
  float* idxo = (float*)d_out + ST_ELEMS;    // (32,64,64) as float
  float* loss = (float*)d_out + LOSS_OFF;    // scalar

  hipMemsetAsync(loss, 0, sizeof(float), stream);  // d_out is poisoned each call
  vq_kernel<<<dim3(512), dim3(512), 0, stream>>>(x, cb, st, idxo, loss);
}

// Round 3
// 191.815 us; speedup vs baseline: 1.2858x; 1.2035x over previous
//
#include <hip/hip_runtime.h>

// Problem constants (B,C,H,W)=(32,64,64,64), code_size=512
#define HWDIM 4096
#define CDIM  64
#define KDIM  512
#define ST_ELEMS   8388608   // 32*64*64*64
#define LOSS_OFF   8519680   // ST_ELEMS + 32*64*64

#define REP64(M) M(0) M(1) M(2) M(3) M(4) M(5) M(6) M(7) M(8) M(9) \
  M(10) M(11) M(12) M(13) M(14) M(15) M(16) M(17) M(18) M(19) \
  M(20) M(21) M(22) M(23) M(24) M(25) M(26) M(27) M(28) M(29) \
  M(30) M(31) M(32) M(33) M(34) M(35) M(36) M(37) M(38) M(39) \
  M(40) M(41) M(42) M(43) M(44) M(45) M(46) M(47) M(48) M(49) \
  M(50) M(51) M(52) M(53) M(54) M(55) M(56) M(57) M(58) M(59) \
  M(60) M(61) M(62) M(63)

// 16-float vector -> s_load_dwordx16 when loaded via constant address space.
typedef float vf16 __attribute__((ext_vector_type(16)));
typedef __attribute__((address_space(4))) const vf16 cvf16;

// numpy fp32 pairwise sum-of-squares of 64 contiguous values (AVX-512 npyv
// emulation) — bit-validated R1-R5.
__device__ __forceinline__ float np_sumsq64(const float a[64]) {
#pragma clang fp contract(off)
  float v[16];
#pragma unroll
  for (int i = 0; i < 16; ++i) {
    float s0 = a[i]      * a[i];
    float s1 = a[i + 16] * a[i + 16];
    float s2 = a[i + 32] * a[i + 32];
    float s3 = a[i + 48] * a[i + 48];
    v[i] = (s0 + s1) + (s2 + s3);
  }
  float t0 = (v[0] + v[8])  + (v[4] + v[12]);
  float t1 = (v[1] + v[9])  + (v[5] + v[13]);
  float t2 = (v[2] + v[10]) + (v[6] + v[14]);
  float t3 = (v[3] + v[11]) + (v[7] + v[15]);
  return (t0 + t2) + (t1 + t3);
}

// R8: 2 pixels per thread. R6/R7 established the main-loop limiter is the
// CU-shared scalar-return rate (~3.2 B/cyc/CU: 2x waves bought 8%, lockstep
// bought 0%). Each s_load_dwordx16 chunk now feeds 2 pixels' FMA chains ->
// total scalar traffic halves (268->134 MB) at an unchanged VALU issue floor
// (54.6us). VGPR doubles (128 pinned x/y regs) -> 2 waves/SIMD; acceptable
// since the scalar pipe, not TLP, is the limiter. Per-pixel FMA chains,
// e-formula, scan order, tie-break all bit-identical to R5-R7; only the
// loss-tree association changes (lane sums 2 pixels first, ~1 ulp).
__global__ __launch_bounds__(256)
__attribute__((amdgpu_waves_per_eu(2, 2)))
void vq_kernel(
    const float* __restrict__ x, const float* __restrict__ cb,
    float* __restrict__ st, float* __restrict__ idxo, float* __restrict__ loss)
{
  __shared__ float sc[KDIM];
  __shared__ unsigned long long mrg[256];
  __shared__ float lred[4];

  const int tid = threadIdx.x;
  const int pix = tid & 127;                       // pixel-pair slot in block
  // readfirstlane: tid>>7 IS wave-uniform (64-aligned waves never straddle a
  // 128 boundary) but divergence analysis can't prove it; force SGPR so the
  // row addresses below stay scalar -> s_load_dwordx16 (vector-load fallback
  // is the known 208us broadcast-BW plateau).
  const int khalf = __builtin_amdgcn_readfirstlane(tid >> 7);
  const int b   = blockIdx.x & 31;                 // batch index
  const int p   = ((blockIdx.x >> 5) << 8) + pix;  // pixel A; pixel B = p+128

  // Constant-AS view of the codebook: wave-uniform row addresses -> the
  // backend emits s_load_dwordx16 (scalar pipe). R1-R5 evidence: rows via
  // vector loads (global OR LDS) all plateau at ~208us = broadcast
  // data-return bandwidth; SGPR rows remove that traffic entirely.
  cvf16* rows = (cvf16*)(uintptr_t)cb;   // row k = chunks [4k .. 4k+3]

  // Per-block codebook sum-of-squares (per-lane k -> divergent: vector loads).
  for (int k = tid; k < KDIM; k += 256) {
    float row[64];
#pragma unroll
    for (int c = 0; c < 64; ++c) row[c] = cb[(k << 6) + c];
    sc[k] = np_sumsq64(row);
  }

  // Load BOTH pixels' points into 128 named, pinned registers.
  const float* xpA = x + (size_t)b * (CDIM * HWDIM) + p;
  const float* xpB = xpA + 128;
#define XLOAD(i) float x##i = xpA[(i) * HWDIM]; asm("" : "+v"(x##i));
#define YLOAD(i) float y##i = xpB[(i) * HWDIM]; asm("" : "+v"(y##i));
  REP64(XLOAD)
  REP64(YLOAD)
#undef XLOAD
#undef YLOAD

  // numpy pairwise sum-of-squares of each pixel (same tree as np_sumsq64,
  // named-register form) — bit-identical to R5.
#define SQT(V, i, j, k2, l) \
    float v##i = ((V##i * V##i) + (V##j * V##j)) + ((V##k2 * V##k2) + (V##l * V##l));
#define SUMSQ_TREE(V, OUT) { \
    _Pragma("clang fp contract(off)") \
    SQT(V,0,16,32,48) SQT(V,1,17,33,49) SQT(V,2,18,34,50) SQT(V,3,19,35,51) \
    SQT(V,4,20,36,52) SQT(V,5,21,37,53) SQT(V,6,22,38,54) SQT(V,7,23,39,55) \
    SQT(V,8,24,40,56) SQT(V,9,25,41,57) SQT(V,10,26,42,58) SQT(V,11,27,43,59) \
    SQT(V,12,28,44,60) SQT(V,13,29,45,61) SQT(V,14,30,46,62) SQT(V,15,31,47,63) \
    float t0 = (v0 + v8)  + (v4 + v12); \
    float t1 = (v1 + v9)  + (v5 + v13); \
    float t2 = (v2 + v10) + (v6 + v14); \
    float t3 = (v3 + v11) + (v7 + v15); \
    OUT = (t0 + t2) + (t1 + t3); }

  float SA, SB;
  SUMSQ_TREE(x, SA)
  SUMSQ_TREE(y, SB)
#undef SUMSQ_TREE
#undef SQT
  __syncthreads();

  // Argmin over this half's 256 codes, 4 rows per iteration, rows streamed
  // through SGPRs in 16-float chunks, each chunk feeding both pixels.
  // Per-chain FMA order is ascending c — bit-identical to R1-R7.
  float bestdA = __builtin_inff(), bestdB = __builtin_inff();
  int   bestiA = 0,                bestiB = 0;
  const int k0 = khalf << 8;

#define FF(T, XI) \
    d0a = __builtin_fmaf(x##XI, c0[T], d0a); \
    d1a = __builtin_fmaf(x##XI, c1[T], d1a); \
    d2a = __builtin_fmaf(x##XI, c2[T], d2a); \
    d3a = __builtin_fmaf(x##XI, c3[T], d3a); \
    d0b = __builtin_fmaf(y##XI, c0[T], d0b); \
    d1b = __builtin_fmaf(y##XI, c1[T], d1b); \
    d2b = __builtin_fmaf(y##XI, c2[T], d2b); \
    d3b = __builtin_fmaf(y##XI, c3[T], d3b);
#define CHUNK(J, A0,A1,A2,A3,A4,A5,A6,A7,A8,A9,A10,A11,A12,A13,A14,A15) \
  { vf16 c0 = rows[rb + (J)];      vf16 c1 = rows[rb + 4 + (J)];        \
    vf16 c2 = rows[rb + 8 + (J)];  vf16 c3 = rows[rb + 12 + (J)];       \
    FF(0,A0) FF(1,A1) FF(2,A2) FF(3,A3) FF(4,A4) FF(5,A5) FF(6,A6)      \
    FF(7,A7) FF(8,A8) FF(9,A9) FF(10,A10) FF(11,A11) FF(12,A12)         \
    FF(13,A13) FF(14,A14) FF(15,A15) }

  for (int k = k0; k < k0 + 256; k += 4) {
    const int rb = k << 2;            // x16-chunk index of row k
    float d0a = 0.f, d1a = 0.f, d2a = 0.f, d3a = 0.f;
    float d0b = 0.f, d1b = 0.f, d2b = 0.f, d3b = 0.f;
    CHUNK(0,  0, 1, 2, 3, 4, 5, 6, 7, 8, 9,10,11,12,13,14,15)
    CHUNK(1, 16,17,18,19,20,21,22,23,24,25,26,27,28,29,30,31)
    CHUNK(2, 32,33,34,35,36,37,38,39,40,41,42,43,44,45,46,47)
    CHUNK(3, 48,49,50,51,52,53,54,55,56,57,58,59,60,61,62,63)
    float e0a, e1a, e2a, e3a, e0b, e1b, e2b, e3b;
    {
#pragma clang fp contract(off)
      e0a = (SA - (d0a + d0a)) + sc[k];
      e1a = (SA - (d1a + d1a)) + sc[k + 1];
      e2a = (SA - (d2a + d2a)) + sc[k + 2];
      e3a = (SA - (d3a + d3a)) + sc[k + 3];
      e0b = (SB - (d0b + d0b)) + sc[k];
      e1b = (SB - (d1b + d1b)) + sc[k + 1];
      e2b = (SB - (d2b + d2b)) + sc[k + 2];
      e3b = (SB - (d3b + d3b)) + sc[k + 3];
    }
    if (e0a < bestdA) { bestdA = e0a; bestiA = k; }
    if (e1a < bestdA) { bestdA = e1a; bestiA = k + 1; }
    if (e2a < bestdA) { bestdA = e2a; bestiA = k + 2; }
    if (e3a < bestdA) { bestdA = e3a; bestiA = k + 3; }
    if (e0b < bestdB) { bestdB = e0b; bestiB = k; }
    if (e1b < bestdB) { bestdB = e1b; bestiB = k + 1; }
    if (e2b < bestdB) { bestdB = e2b; bestiB = k + 2; }
    if (e3b < bestdB) { bestdB = e3b; bestiB = k + 3; }
  }
#undef CHUNK
#undef FF

  // Cross-half argmin merge. Distances are ~64 (strictly positive) so fp32
  // bit patterns order identically to the floats; packing idx in the low
  // word makes u64-min reproduce "first minimum wins" exactly.
  unsigned long long pkA =
      ((unsigned long long)__float_as_uint(bestdA) << 32) | (unsigned)bestiA;
  unsigned long long pkB =
      ((unsigned long long)__float_as_uint(bestdB) << 32) | (unsigned)bestiB;
  if (khalf) { mrg[pix] = pkA; mrg[pix + 128] = pkB; }
  __syncthreads();

  float lsum = 0.f;
  if (!khalf) {
    { unsigned long long o = mrg[pix];       if (o < pkA) pkA = o; }
    { unsigned long long o = mrg[pix + 128]; if (o < pkB) pkB = o; }
    bestiA = (int)(pkA & 0xffffffffull);
    bestiB = (int)(pkB & 0xffffffffull);

    // Gather chosen code rows (per-lane divergent -> vector loads), write st
    // (coalesced: lane = consecutive p), accumulate loss partials.
    const float* crowA = cb + (bestiA << 6);
    const float* crowB = cb + (bestiB << 6);
    float* stpA = st + (size_t)b * (CDIM * HWDIM) + p;
    float* stpB = stpA + 128;
    float lsumA = 0.f, lsumB = 0.f;
#define EPIA(i) { float cv = crowA[i]; float df; \
    { _Pragma("clang fp contract(off)") df = cv - x##i; } \
    lsumA = __builtin_fmaf(df, df, lsumA); stpA[(i) * HWDIM] = cv; }
#define EPIB(i) { float cv = crowB[i]; float df; \
    { _Pragma("clang fp contract(off)") df = cv - y##i; } \
    lsumB = __builtin_fmaf(df, df, lsumB); stpB[(i) * HWDIM] = cv; }
    REP64(EPIA)
    REP64(EPIB)
#undef EPIA
#undef EPIB

    // indices[b, p] as float (d_out is one flat float32 buffer).
    idxo[b * HWDIM + p]       = (float)bestiA;
    idxo[b * HWDIM + p + 128] = (float)bestiB;

    lsum = lsumA + lsumB;
  }

  // Block reduce loss, one atomic per block. Waves 2-3 contribute exact
  // zeros (t + 0.0f == t bitwise for the nonnegative sums here).
#pragma unroll
  for (int off = 32; off > 0; off >>= 1) lsum += __shfl_down(lsum, off);
  if ((tid & 63) == 0) lred[tid >> 6] = lsum;
  __syncthreads();
  if (tid == 0) {
    float t = (lred[0] + lred[1]) + (lred[2] + lred[3]);
    atomicAdd(loss, t * (1.25f / 8388608.f));
  }
}

extern "C" void kernel_launch(void* const* d_in, const int* in_sizes, int n_in,
                              void* d_out, int out_size, void* d_ws, size_t ws_size,
                              hipStream_t stream) {
  const float* x  = (const float*)d_in[0];   // (32,64,64,64) fp32
  const float* cb = (const float*)d_in[1];   // (512,64) fp32
  float* st   = (float*)d_out;               // (32,64,64,64)
  float* idxo = (float*)d_out + ST_ELEMS;    // (32,64,64) as float
  float* loss = (float*)d_out + LOSS_OFF;    // scalar

  hipMemsetAsync(loss, 0, sizeof(float), stream);  // d_out is poisoned each call
  vq_kernel<<<dim3(512), dim3(256), 0, stream>>>(x, cb, st, idxo, loss);
}